// Round 3
// baseline (112.057 us; speedup 1.0000x reference)
//
#include <hip/hip_runtime.h>
#include <hip/hip_bf16.h>
#include <math.h>

// NT-Xent loss, N=4096, D=256, symmetric triangular GEMM, 256x128 blocks.
// loss = (1/2N) * sum_i [ 2 + log( sum_{j != i} exp(2*dot_ij - 2) ) - 2*dot(zn_i, zn_pair(i)) ]
// K1: normalize rows -> bf16 zn in ws; zero rowtotal[8192] and out.
// K2: tiles (ib:32 x 256 rows, jb:64 x 128 cols), jb >= 2*ib (1056 blocks).
//     4 waves, wave tile 128x64 (8x4 of 16x16x32 MFMA) -> LDS-read/MFMA balanced.
//     Fused epilogue: uniform j>i mask (evaluated only in the 2 near-diag tiles),
//     exp row-sums + col-sums -> rowtotal via one atomic per row/col,
//     pair tiles (jb==2ib+32/33) accumulate -2*pair_dot terms into out.
// K3: loss += sum_i (2 + log(rowtotal[i])) / 2N.

using short8  = __attribute__((ext_vector_type(8))) short;
using floatx4 = __attribute__((ext_vector_type(4))) float;

constexpr int TWO_N = 8192;
constexpr int DIM   = 256;
constexpr int NBLKS = 1056;   // sum_{ib=0}^{31} (64 - 2*ib)
constexpr float INV2N = 1.0f / 8192.0f;

__device__ static inline unsigned short f2bf(float f) {
  unsigned u = __float_as_uint(f);
  return (unsigned short)((u + 0x7fffu + ((u >> 16) & 1u)) >> 16);  // RNE
}

__device__ static inline void async_copy16(const __hip_bfloat16* g, __hip_bfloat16* l) {
  __builtin_amdgcn_global_load_lds(
      (const __attribute__((address_space(1))) void*)(const void*)g,
      (__attribute__((address_space(3))) void*)(void*)l, 16, 0, 0);
}

// ---------------- K1: normalize + cast to bf16, zero accumulators ----------------
__global__ __launch_bounds__(256) void k_normalize(
    const float* __restrict__ zi, const float* __restrict__ zj,
    __hip_bfloat16* __restrict__ zn, float* __restrict__ rowtotal,
    float* __restrict__ out)
{
  if (blockIdx.x == 0 && threadIdx.x == 0) out[0] = 0.0f;
  if (blockIdx.x < 32) rowtotal[blockIdx.x * 256 + threadIdx.x] = 0.0f;

  const int lane = threadIdx.x & 63;
  const int wave = threadIdx.x >> 6;
  const int row  = blockIdx.x * 4 + wave;
  const float* src = (row < 4096) ? (zi + (size_t)row * DIM)
                                  : (zj + (size_t)(row - 4096) * DIM);
  float4 v = reinterpret_cast<const float4*>(src)[lane];
  float ss = v.x * v.x + v.y * v.y + v.z * v.z + v.w * v.w;
#pragma unroll
  for (int m = 32; m >= 1; m >>= 1) ss += __shfl_xor(ss, m, 64);
  float inv = 1.0f / fmaxf(sqrtf(ss), 1e-8f);
  ushort4 o;
  o.x = f2bf(v.x * inv); o.y = f2bf(v.y * inv);
  o.z = f2bf(v.z * inv); o.w = f2bf(v.w * inv);
  reinterpret_cast<ushort4*>(zn + (size_t)row * DIM)[lane] = o;
}

// ---------------- K2: triangular GEMM + fused epilogue ----------------
// LDS tiles [rows][64] bf16, 8 x 16B slots/row, phys_slot = logical ^ (row&7).
__global__ __launch_bounds__(256, 2) void k_simexp(
    const __hip_bfloat16* __restrict__ Z, float* __restrict__ rowtotal,
    float* __restrict__ out)
{
  __shared__ __align__(16) __hip_bfloat16 As[256 * 64];  // 32 KB
  __shared__ __align__(16) __hip_bfloat16 Bs[128 * 64];  // 16 KB
  __shared__ float rowsum[2][256];                       // [wn][row]
  __shared__ float colsum[2][128];                       // [wm][col]

  const int tid  = threadIdx.x;
  const int lane = tid & 63;
  const int wave = tid >> 6;
  const int wm   = wave >> 1;   // output row half (128 rows each)
  const int wn   = wave & 1;    // output col half (64 cols each)

  // decode blockIdx.x -> (ib, jb) with jb >= 2*ib; cum(ib) = ib*(65-ib)
  const int u = blockIdx.x;
  int ib = (int)((65.0f - sqrtf(4225.0f - 4.0f * (float)u)) * 0.5f);
  while ((ib + 1) * (64 - ib) <= u) ++ib;      // cum(ib+1) = (ib+1)*(65-(ib+1))
  while (ib * (65 - ib) > u) --ib;
  const int jb = 2 * ib + (u - ib * (65 - ib));

  const int i0 = ib * 256;
  const int j0 = jb * 128;
  const bool neardiag = (jb <= 2 * ib + 1);
  const bool pairblk  = (jb == 2 * ib + 32) || (jb == 2 * ib + 33);

  floatx4 acc[8][4] = {};

  const int lane7 = lane & 7;
  const int sub   = lane >> 3;               // 0..7 subrow within 8-row segment
  const int gkoff = ((lane7 ^ sub) << 3);    // swizzled logical 16B slot to fetch
  const int q     = lane >> 4;               // 0..3
  const int c16   = lane & 15;

  for (int kk = 0; kk < 4; ++kk) {
    const int k0 = kk * 64;
    // staging: 48 one-KB calls (32 A + 16 B), 12 per wave; 8 rows per call.
#pragma unroll
    for (int c = 0; c < 12; ++c) {
      const int t = wave * 12 + c;
      const bool isA = (t < 32);
      const int seg = isA ? t : (t - 32);
      const __hip_bfloat16* gp =
          Z + (size_t)((isA ? i0 : j0) + seg * 8 + sub) * DIM + k0 + gkoff;
      async_copy16(gp, (isA ? As : Bs) + seg * 512);  // + lane*16B implicit
    }
    __syncthreads();

#pragma unroll
    for (int ks = 0; ks < 2; ++ks) {
      const int phys = (ks * 4 + q) ^ lane7;  // physical 16B slot for this lane
      short8 a[8], b[4];
#pragma unroll
      for (int mt = 0; mt < 8; ++mt)
        a[mt] = *reinterpret_cast<const short8*>(
            As + (wm * 128 + mt * 16 + c16) * 64 + phys * 8);
#pragma unroll
      for (int nt = 0; nt < 4; ++nt)
        b[nt] = *reinterpret_cast<const short8*>(
            Bs + (wn * 64 + nt * 16 + c16) * 64 + phys * 8);
#pragma unroll
      for (int mt = 0; mt < 8; ++mt)
#pragma unroll
        for (int nt = 0; nt < 4; ++nt)
          acc[mt][nt] = __builtin_amdgcn_mfma_f32_16x16x32_bf16(
              a[mt], b[nt], acc[mt][nt], 0, 0, 0);
    }
    __syncthreads();
  }

  // ---- epilogue ----
  // C/D layout: col = c16 (within nt-tile), row = q*4 + reg (within mt-tile).
  float colacc[4] = {0.f, 0.f, 0.f, 0.f};
  float pc = 0.f;
  const int ibase = i0 + wm * 128 + (q << 2);
  const int jbase = j0 + wn * 64 + c16;

#pragma unroll
  for (int mt = 0; mt < 8; ++mt) {
#pragma unroll
    for (int reg = 0; reg < 4; ++reg) {
      const int i = ibase + mt * 16 + reg;
      float s = 0.0f;
#pragma unroll
      for (int nt = 0; nt < 4; ++nt) {
        const int j = jbase + nt * 16;
        float e = __expf(2.0f * acc[mt][nt][reg] - 2.0f);
        if (neardiag && j <= i) e = 0.0f;   // strict upper triangle only
        s += e;
        colacc[nt] += e;
        if (pairblk && (j - i == 4096)) pc += acc[mt][nt][reg];
      }
      s += __shfl_xor(s, 1, 64);
      s += __shfl_xor(s, 2, 64);
      s += __shfl_xor(s, 4, 64);
      s += __shfl_xor(s, 8, 64);
      if (c16 == 0)
        rowsum[wn][wm * 128 + mt * 16 + (q << 2) + reg] = s;  // unique writer
    }
  }

#pragma unroll
  for (int nt = 0; nt < 4; ++nt) {
    float cs = colacc[nt];
    cs += __shfl_xor(cs, 16, 64);
    cs += __shfl_xor(cs, 32, 64);
    if (lane < 16) colsum[wm][wn * 64 + nt * 16 + lane] = cs;  // unique writer
  }

  if (pairblk) {
#pragma unroll
    for (int m = 32; m >= 1; m >>= 1) pc += __shfl_xor(pc, m, 64);
    // each pair elem covers rows i and i+4096: loss += -2*(2*dot) per pair
    if (lane == 0) atomicAdd(out, -4.0f * pc * INV2N);
  }

  __syncthreads();
  atomicAdd(&rowtotal[i0 + tid], rowsum[0][tid] + rowsum[1][tid]);
  if (tid < 128)
    atomicAdd(&rowtotal[j0 + tid], colsum[0][tid] + colsum[1][tid]);
}

// ---------------- K3: finalize (logs + reduce) ----------------
__global__ __launch_bounds__(256) void k_finalize(
    const float* __restrict__ rowtotal, float* __restrict__ out)
{
  __shared__ float wsum[4];
  const int lane = threadIdx.x & 63;
  const int wave = threadIdx.x >> 6;
  const int row  = blockIdx.x * 256 + threadIdx.x;
  float v = 2.0f + __logf(rowtotal[row]);
#pragma unroll
  for (int m = 32; m >= 1; m >>= 1) v += __shfl_xor(v, m, 64);
  if (lane == 0) wsum[wave] = v;
  __syncthreads();
  if (threadIdx.x == 0)
    atomicAdd(out, (wsum[0] + wsum[1] + wsum[2] + wsum[3]) * INV2N);
}

// ---------------- launch ----------------
extern "C" void kernel_launch(void* const* d_in, const int* in_sizes, int n_in,
                              void* d_out, int out_size, void* d_ws, size_t ws_size,
                              hipStream_t stream) {
  const float* zi = (const float*)d_in[0];
  const float* zj = (const float*)d_in[1];
  float* out = (float*)d_out;

  __hip_bfloat16* zn = (__hip_bfloat16*)d_ws;                        // 8192*256*2 = 4 MB
  float* rowtotal = (float*)((char*)d_ws + (size_t)TWO_N * DIM * 2); // 8192*4 = 32 KB

  k_normalize<<<dim3(TWO_N / 4), dim3(256), 0, stream>>>(zi, zj, zn, rowtotal, out);
  k_simexp<<<dim3(NBLKS), dim3(256), 0, stream>>>(zn, rowtotal, out);
  k_finalize<<<dim3(TWO_N / 256), dim3(256), 0, stream>>>(rowtotal, out);
}